// Round 14
// baseline (62.560 us; speedup 1.0000x reference)
//
#include <hip/hip_runtime.h>
#include <math.h>

#define NN   65536
#define DEGC 16
#define DD   64
#define DD2  128
#define BB   1024
#define NEGC 10
#define NROWS (2 * BB + NEGC)      // 2058
#define NEDGE (NROWS * DEGC)       // 32928

__device__ __forceinline__ float tanh_fast(float x) {
    float t = __expf(2.0f * x);
    return 1.0f - 2.0f * __builtin_amdgcn_rcpf(t + 1.0f);
}

__device__ __forceinline__ unsigned short f2bf(float v) {   // RNE bf16 pack
    unsigned int x = __float_as_uint(v);
    x += 0x7FFFu + ((x >> 16) & 1u);
    return (unsigned short)(x >> 16);
}
__device__ __forceinline__ float bf2f(unsigned short u) {
    return __uint_as_float(((unsigned int)u) << 16);
}

// ---------------------------------------------------------------------------
// K1: dense index-free GEMMs, bf16 outputs (R12/R13-proven, unchanged):
//   Pb[n][j] = bf16( feat[n]@W1a[j] + b1[j] );  Qb[n][j] = bf16( feat[n]@W1b[j] )
// ---------------------------------------------------------------------------
__global__ __launch_bounds__(256) void pq_gemm_kernel(
    const float* __restrict__ feat, const float* __restrict__ W1,
    const float* __restrict__ b1,
    unsigned short* __restrict__ Pb, unsigned short* __restrict__ Qb) {

    __shared__ float4 qa[1024];           // 16 KB: W1[j][4i4..]
    __shared__ float4 qb[1024];           // 16 KB: W1[j][64+4i4..]
    int tid = threadIdx.x;
    {
        int j = tid & 63, g = tid >> 6;
        #pragma unroll
        for (int t = 0; t < 4; ++t) {
            int i4 = g * 4 + t;
            qa[(i4 << 6) | j] = *(const float4*)(W1 + j * DD2 + i4 * 4);
            qb[(i4 << 6) | j] = *(const float4*)(W1 + j * DD2 + DD + i4 * 4);
        }
    }
    __syncthreads();

    int lane = tid & 63;
    int w = tid >> 6;
    int nbase = __builtin_amdgcn_readfirstlane((blockIdx.x * 4 + w) * 4);

    const float* f0 = feat + (size_t)(nbase + 0) * DD;
    const float* f1 = feat + (size_t)(nbase + 1) * DD;
    const float* f2 = feat + (size_t)(nbase + 2) * DD;
    const float* f3 = feat + (size_t)(nbase + 3) * DD;

    float bias = b1[lane];
    float pa0 = bias, pa1 = bias, pa2 = bias, pa3 = bias;
    float qv0 = 0.f, qv1 = 0.f, qv2 = 0.f, qv3 = 0.f;
    #pragma unroll
    for (int i4 = 0; i4 < 16; ++i4) {
        float4 wa = qa[(i4 << 6) | lane];          // ds_read_b128
        float4 wb = qb[(i4 << 6) | lane];
        float4 c0 = *(const float4*)(f0 + i4 * 4); // uniform -> broadcast
        float4 c1 = *(const float4*)(f1 + i4 * 4);
        float4 c2 = *(const float4*)(f2 + i4 * 4);
        float4 c3 = *(const float4*)(f3 + i4 * 4);
        pa0 += c0.x * wa.x + c0.y * wa.y + c0.z * wa.z + c0.w * wa.w;
        pa1 += c1.x * wa.x + c1.y * wa.y + c1.z * wa.z + c1.w * wa.w;
        pa2 += c2.x * wa.x + c2.y * wa.y + c2.z * wa.z + c2.w * wa.w;
        pa3 += c3.x * wa.x + c3.y * wa.y + c3.z * wa.z + c3.w * wa.w;
        qv0 += c0.x * wb.x + c0.y * wb.y + c0.z * wb.z + c0.w * wb.w;
        qv1 += c1.x * wb.x + c1.y * wb.y + c1.z * wb.z + c1.w * wb.w;
        qv2 += c2.x * wb.x + c2.y * wb.y + c2.z * wb.z + c2.w * wb.w;
        qv3 += c3.x * wb.x + c3.y * wb.y + c3.z * wb.z + c3.w * wb.w;
    }
    Pb[(size_t)(nbase + 0) * DD + lane] = f2bf(pa0);
    Pb[(size_t)(nbase + 1) * DD + lane] = f2bf(pa1);
    Pb[(size_t)(nbase + 2) * DD + lane] = f2bf(pa2);
    Pb[(size_t)(nbase + 3) * DD + lane] = f2bf(pa3);
    Qb[(size_t)(nbase + 0) * DD + lane] = f2bf(qv0);
    Qb[(size_t)(nbase + 1) * DD + lane] = f2bf(qv1);
    Qb[(size_t)(nbase + 2) * DD + lane] = f2bf(qv2);
    Qb[(size_t)(nbase + 3) * DD + lane] = f2bf(qv3);
}

// ---------------------------------------------------------------------------
// K2: per-ROW fused edge-tanh + sum (kills the h1 round-trip entirely).
// Block = graph row r. Wave w owns edges k=4w..4w+3; group g (16 lanes) owns
// edge k=4w+g; lane (g,q) owns j=4q..4q+3 (R13's widened 8B/lane gather).
//   csum2[r][j] = sum_{k<16} tanh( Pb[n_k][j] + sum_i Qb[adj[n_k][i]][j] )
// Reduce: shfl_xor across the 4 groups, LDS across the 4 waves.
// ---------------------------------------------------------------------------
__global__ __launch_bounds__(256) void row_kernel(
    const int* __restrict__ adj,
    const int* __restrict__ in1, const int* __restrict__ in2,
    const int* __restrict__ neg,
    const unsigned short* __restrict__ Pb, const unsigned short* __restrict__ Qb,
    float* __restrict__ csum2) {

    __shared__ float cs[4][DD];           // 1 KB cross-wave partials

    int tid = threadIdx.x;
    int lane = tid & 63;
    int w = tid >> 6;
    int g = lane >> 4;                    // edge slot within wave
    int q = lane & 15;                    // j-slice: j = 4q..4q+3
    int r = blockIdx.x;

    int node = (r < BB) ? in1[r] : (r < 2 * BB ? in2[r - BB] : neg[r - 2 * BB]);
    node = __builtin_amdgcn_readfirstlane(node);
    const int* arow = adj + node * DEGC + w * 4;   // uniform -> s_loads
    int n0 = __builtin_amdgcn_readfirstlane(arow[0]);
    int n1 = __builtin_amdgcn_readfirstlane(arow[1]);
    int n2 = __builtin_amdgcn_readfirstlane(arow[2]);
    int n3 = __builtin_amdgcn_readfirstlane(arow[3]);
    int n_g = (g == 0) ? n0 : (g == 1) ? n1 : (g == 2) ? n2 : n3;

    // lane q holds neighbor id q of its group's edge
    int nbr = adj[(size_t)n_g * DEGC + q];

    // self term (P row of this edge's node)
    float a0, a1, a2, a3;
    {
        unsigned long long v = *(const unsigned long long*)(Pb + (size_t)n_g * DD + q * 4);
        a0 = bf2f((unsigned short)(v));
        a1 = bf2f((unsigned short)(v >> 16));
        a2 = bf2f((unsigned short)(v >> 32));
        a3 = bf2f((unsigned short)(v >> 48));
    }
    // 16 widened gathers: each instruction pulls 4 Qb rows (512B) per wave
    #pragma unroll
    for (int i = 0; i < DEGC; ++i) {
        int row = __shfl(nbr, g * 16 + i, 64);
        unsigned long long v = *(const unsigned long long*)(Qb + (size_t)row * DD + q * 4);
        a0 += bf2f((unsigned short)(v));
        a1 += bf2f((unsigned short)(v >> 16));
        a2 += bf2f((unsigned short)(v >> 32));
        a3 += bf2f((unsigned short)(v >> 48));
    }
    a0 = tanh_fast(a0); a1 = tanh_fast(a1);
    a2 = tanh_fast(a2); a3 = tanh_fast(a3);

    // sum over the 4 groups (edges) in this wave
    a0 += __shfl_xor(a0, 16, 64); a0 += __shfl_xor(a0, 32, 64);
    a1 += __shfl_xor(a1, 16, 64); a1 += __shfl_xor(a1, 32, 64);
    a2 += __shfl_xor(a2, 16, 64); a2 += __shfl_xor(a2, 32, 64);
    a3 += __shfl_xor(a3, 16, 64); a3 += __shfl_xor(a3, 32, 64);

    if (g == 0) {
        cs[w][q * 4 + 0] = a0;
        cs[w][q * 4 + 1] = a1;
        cs[w][q * 4 + 2] = a2;
        cs[w][q * 4 + 3] = a3;
    }
    __syncthreads();
    if (w == 0) {
        float s = cs[0][lane] + cs[1][lane] + cs[2][lane] + cs[3][lane];
        csum2[(size_t)r * DD + lane] = s;
    }
}

// ---------------------------------------------------------------------------
// K3: GEMV2 + normalize (R3-proven shape): 8 rows/block, W2 float4 LDS,
// c-operands (feat row, csum2 row) via uniform-address broadcast float4.
// ---------------------------------------------------------------------------
__global__ __launch_bounds__(256) void gemv2_kernel(
    const float* __restrict__ feat,
    const int* __restrict__ in1, const int* __restrict__ in2,
    const int* __restrict__ neg,
    const float* __restrict__ csum2, const float* __restrict__ W2,
    const float* __restrict__ b2, float* __restrict__ out) {

    __shared__ float4 q2[4096];          // 64 KB
    int tid = threadIdx.x;
    {
        int j = tid & 127, g0 = tid >> 7;
        #pragma unroll
        for (int g = 0; g < 16; ++g) {
            int i4 = g0 * 16 + g;
            q2[(i4 << 7) | j] = *(const float4*)(W2 + j * DD2 + (i4 << 2));
        }
    }
    __syncthreads();

    int lane = tid & 63;
    int wv = blockIdx.x * 4 + (tid >> 6);
    int r0 = wv * 2, r1 = wv * 2 + 1;
    bool a0 = r0 < NROWS, a1 = r1 < NROWS;
    if (!a0) return;

    int node0 = (r0 < BB) ? in1[r0] : (r0 < 2 * BB ? in2[r0 - BB] : neg[r0 - 2 * BB]);
    int node1 = a1 ? ((r1 < BB) ? in1[r1] : (r1 < 2 * BB ? in2[r1 - BB] : neg[r1 - 2 * BB])) : node0;
    node0 = __builtin_amdgcn_readfirstlane(node0);
    node1 = __builtin_amdgcn_readfirstlane(node1);
    const float* cf0 = feat + (size_t)node0 * DD;
    const float* cf1 = feat + (size_t)node1 * DD;
    const float* cs0 = csum2 + (size_t)r0 * DD;
    const float* cs1 = csum2 + (size_t)(a1 ? r1 : r0) * DD;

    float A0 = b2[lane], B0 = b2[DD + lane];
    float A1 = A0, B1 = B0;

    #pragma unroll
    for (int i4 = 0; i4 < 16; ++i4) {
        float4 wA = q2[(i4 << 7) | lane];
        float4 wB = q2[(i4 << 7) | (64 + lane)];
        float4 c0 = *(const float4*)(cf0 + (i4 << 2));
        float4 c1 = *(const float4*)(cf1 + (i4 << 2));
        A0 += c0.x * wA.x + c0.y * wA.y + c0.z * wA.z + c0.w * wA.w;
        B0 += c0.x * wB.x + c0.y * wB.y + c0.z * wB.z + c0.w * wB.w;
        A1 += c1.x * wA.x + c1.y * wA.y + c1.z * wA.z + c1.w * wA.w;
        B1 += c1.x * wB.x + c1.y * wB.y + c1.z * wB.z + c1.w * wB.w;
    }
    #pragma unroll
    for (int i4 = 0; i4 < 16; ++i4) {
        float4 wA = q2[((16 + i4) << 7) | lane];
        float4 wB = q2[((16 + i4) << 7) | (64 + lane)];
        float4 c0 = *(const float4*)(cs0 + (i4 << 2));
        float4 c1 = *(const float4*)(cs1 + (i4 << 2));
        A0 += c0.x * wA.x + c0.y * wA.y + c0.z * wA.z + c0.w * wA.w;
        B0 += c0.x * wB.x + c0.y * wB.y + c0.z * wB.z + c0.w * wB.w;
        A1 += c1.x * wA.x + c1.y * wA.y + c1.z * wA.z + c1.w * wA.w;
        B1 += c1.x * wB.x + c1.y * wB.y + c1.z * wB.z + c1.w * wB.w;
    }

    {
        float ss = A0 * A0 + B0 * B0;
        #pragma unroll
        for (int off = 32; off > 0; off >>= 1) ss += __shfl_xor(ss, off, 64);
        float inv = 1.0f / fmaxf(sqrtf(ss), 1e-12f);
        out[(size_t)r0 * DD2 + lane]      = A0 * inv;
        out[(size_t)r0 * DD2 + DD + lane] = B0 * inv;
    }
    if (a1) {
        float ss = A1 * A1 + B1 * B1;
        #pragma unroll
        for (int off = 32; off > 0; off >>= 1) ss += __shfl_xor(ss, off, 64);
        float inv = 1.0f / fmaxf(sqrtf(ss), 1e-12f);
        out[(size_t)r1 * DD2 + lane]      = A1 * inv;
        out[(size_t)r1 * DD2 + DD + lane] = B1 * inv;
    }
}

// ---------------------------------------------------------------------------
extern "C" void kernel_launch(void* const* d_in, const int* in_sizes, int n_in,
                              void* d_out, int out_size, void* d_ws, size_t ws_size,
                              hipStream_t stream) {
    const float* feat = (const float*)d_in[0];
    const int*   adj  = (const int*)d_in[1];
    const int*   in1  = (const int*)d_in[2];
    const int*   in2  = (const int*)d_in[3];
    const int*   neg  = (const int*)d_in[4];
    const float* W1   = (const float*)d_in[5];
    const float* b1   = (const float*)d_in[6];
    const float* W2   = (const float*)d_in[7];
    const float* b2   = (const float*)d_in[8];
    float* out = (float*)d_out;

    // ws (~17.3 MB): Pb[NN][64] bf16 | Qb[NN][64] bf16 | csum2[NROWS][64] f32
    char* p = (char*)d_ws;
    unsigned short* Pb = (unsigned short*)p;
    size_t off = (size_t)NN * DD * sizeof(unsigned short);
    unsigned short* Qb = (unsigned short*)(p + off);
    off += (size_t)NN * DD * sizeof(unsigned short);
    float* csum2 = (float*)(p + off);

    pq_gemm_kernel<<<NN / 16, 256, 0, stream>>>(feat, W1, b1, Pb, Qb);
    row_kernel<<<NROWS, 256, 0, stream>>>(adj, in1, in2, neg, Pb, Qb, csum2);
    gemv2_kernel<<<(NROWS + 7) / 8, 256, 0, stream>>>(
        feat, in1, in2, neg, csum2, W2, b2, out);
}